// Round 3
// baseline (1394.999 us; speedup 1.0000x reference)
//
#include <hip/hip_runtime.h>
#include <hip/hip_bf16.h>

// Fully-fused Swin shifted-window attention, MI355X gfx950.
// B=8, H=W=128, D=256, NHEAD=8, DK=32, WS=8, NH=NW=16, WSQ=64, SHIFT=4.
// prep: weight transposes (bf16) + fused (mask|rel-bias) ADD table.
// fused_k: 1 block = 1 window (64 pixels), 4 waves, 2 heads/wave.
//   Per head: Q/K/V proj (A from global f32 x/z, B from L2-hot Wt) -> LDS,
//   QK^T -> softmax -> P (overwrites Q/K region) -> PV -> o regs.
//   att (both heads) -> LDS -> barrier -> O-GEMM -> f32 d_out.

typedef __bf16  bf16x8 __attribute__((ext_vector_type(8)));
typedef short   short8 __attribute__((ext_vector_type(8)));
typedef short   short4v __attribute__((ext_vector_type(4)));
typedef float   f32x4  __attribute__((ext_vector_type(4)));

#define SCALE_F 0.17677669529663687f

// per-wave LDS region (shorts): [0,2560) Q(pitch40) / P,att(pitch72) overlap
//                               [2560,5120) K(pitch40)
//                               [5120,7424) V transposed [32 dk][72]
#define WREG 7424

__device__ __forceinline__ short f2bs(float f){
    __hip_bfloat16 h = __float2bfloat16(f);
    return __builtin_bit_cast(short, h);
}
__device__ __forceinline__ int strip3(int r, int c){
    if (c == 0) return 0;
    if (c == 1) return (r < 4) ? 0 : 1;
    return (r < 4) ? 2 : 0;
}
__device__ __forceinline__ bf16x8 ld_cvt(const float* __restrict__ p){
    float4 a0 = *reinterpret_cast<const float4*>(p);
    float4 a1 = *reinterpret_cast<const float4*>(p + 4);
    short8 t;
    t[0]=f2bs(a0.x); t[1]=f2bs(a0.y); t[2]=f2bs(a0.z); t[3]=f2bs(a0.w);
    t[4]=f2bs(a1.x); t[5]=f2bs(a1.y); t[6]=f2bs(a1.z); t[7]=f2bs(a1.w);
    return __builtin_bit_cast(bf16x8, t);
}

// ---------------- prep: weight transpose->bf16 + ADD table ------------------
__global__ __launch_bounds__(256) void prep_k(const float* __restrict__ Wq,
                                              const float* __restrict__ Wkv,
                                              const float* __restrict__ Wo,
                                              const float* __restrict__ rel,
                                              short* __restrict__ Wqt,
                                              short* __restrict__ Wkvt,
                                              short* __restrict__ Wot,
                                              float* __restrict__ ADD){
    int i = blockIdx.x * 256 + threadIdx.x;
    if (i < 65536){
        int n = i >> 8, k = i & 255;
        Wqt[i] = f2bs(Wq[k * 256 + n]);
    } else if (i < 196608){
        int j = i - 65536;
        int n = j >> 8, k = j & 255;
        Wkvt[j] = f2bs(Wkv[k * 512 + n]);
    } else if (i < 262144){
        int j = i - 196608;
        int n = j >> 8, k = j & 255;
        Wot[j] = f2bs(Wo[k * 256 + n]);
    } else {
        int j = i - 262144;
        int k = j & 63, q = (j >> 6) & 63, head = (j >> 12) & 7, cls = j >> 15;
        int wiC = cls / 3, wjC = cls - wiC * 3;
        int qr = q >> 3, qc = q & 7, kr = k >> 3, kc = k & 7;
        int lq = strip3(qr, wiC) * 3 + strip3(qc, wjC);
        int lk = strip3(kr, wiC) * 3 + strip3(kc, wjC);
        float pe = rel[((qr - kr + 7) * 15 + (qc - kc + 7)) * 8 + head];
        ADD[j] = (lq != lk) ? -1e9f : pe;
    }
}

// projection GEMM, N=32 (one head-slice): A gathered from global f32, B = Wt (bf16)
// VT=false: dst[pix][col] pitch 40.  VT=true: dst[col][pix] pitch 72 (b64 writes).
template<bool VT>
__device__ __forceinline__ void proj32(const float* __restrict__ A, const int* __restrict__ abase,
                                       const short* __restrict__ Wt, int c0,
                                       const float* __restrict__ bias,
                                       short* dst, int l15, int g){
    f32x4 acc[4][2];
    const f32x4 zero = {0.f,0.f,0.f,0.f};
#pragma unroll
    for (int mi=0;mi<4;++mi){ acc[mi][0]=zero; acc[mi][1]=zero; }
#pragma unroll
    for (int kt=0; kt<8; ++kt){
        bf16x8 af[4], bfr[2];
#pragma unroll
        for (int mi=0;mi<4;++mi)
            af[mi] = ld_cvt(A + abase[mi] + kt*32 + g*8);
#pragma unroll
        for (int nj=0;nj<2;++nj)
            bfr[nj] = *reinterpret_cast<const bf16x8*>(Wt + (size_t)(c0 + nj*16 + l15)*256 + kt*32 + g*8);
#pragma unroll
        for (int mi=0;mi<4;++mi)
#pragma unroll
            for (int nj=0;nj<2;++nj)
                acc[mi][nj] = __builtin_amdgcn_mfma_f32_16x16x32_bf16(af[mi], bfr[nj], acc[mi][nj], 0,0,0);
    }
#pragma unroll
    for (int nj=0;nj<2;++nj){
        float bv = bias[c0 + nj*16 + l15];
        if (VT){
#pragma unroll
            for (int mi=0;mi<4;++mi){
                short4v t;
#pragma unroll
                for (int r=0;r<4;++r) t[r] = f2bs(acc[mi][nj][r] + bv);
                *reinterpret_cast<short4v*>(dst + (nj*16 + l15)*72 + mi*16 + g*4) = t;
            }
        } else {
#pragma unroll
            for (int mi=0;mi<4;++mi)
#pragma unroll
                for (int r=0;r<4;++r)
                    dst[(mi*16 + g*4 + r)*40 + nj*16 + l15] = f2bs(acc[mi][nj][r] + bv);
        }
    }
}

// one head: Q/K/V proj -> S -> softmax -> P -> PV -> o (normalized)
__device__ __forceinline__ void do_head(const float* __restrict__ x, const float* __restrict__ z,
    const short* __restrict__ Wqt, const short* __restrict__ Wkvt,
    const float* __restrict__ bq, const float* __restrict__ bkv,
    const float* __restrict__ addb, int head, const int* __restrict__ abase,
    short* R, int l15, int g, f32x4 (&o)[4][2]){
    const int c0 = head * 32;
    proj32<false>(x, abase, Wqt,  c0,       bq,  R,        l15, g);   // Q -> [0,2560)
    proj32<false>(z, abase, Wkvt, c0,       bkv, R + 2560, l15, g);   // K -> [2560,5120)
    proj32<true >(z, abase, Wkvt, 256 + c0, bkv, R + 5120, l15, g);   // V^T -> [5120,7424)

    // S = Q K^T (64x64)
    bf16x8 aq[4], bk[4];
#pragma unroll
    for (int mi=0;mi<4;++mi) aq[mi] = *reinterpret_cast<const bf16x8*>(R + (mi*16 + l15)*40 + g*8);
#pragma unroll
    for (int ni=0;ni<4;++ni) bk[ni] = *reinterpret_cast<const bf16x8*>(R + 2560 + (ni*16 + l15)*40 + g*8);
    const f32x4 zero = {0.f,0.f,0.f,0.f};
    f32x4 s[4][4];
#pragma unroll
    for (int mi=0;mi<4;++mi)
#pragma unroll
        for (int ni=0;ni<4;++ni)
            s[mi][ni] = __builtin_amdgcn_mfma_f32_16x16x32_bf16(aq[mi], bk[ni], zero, 0,0,0);

    // scale + (mask|bias), wave-parallel softmax, unnormalized P -> R (pitch 72)
    float rs[4][4];
#pragma unroll
    for (int mi=0;mi<4;++mi){
        const int qbase = mi*16 + g*4;
#pragma unroll
        for (int ni=0;ni<4;++ni){
            const int k = ni*16 + l15;
#pragma unroll
            for (int r=0;r<4;++r)
                s[mi][ni][r] = fmaf(s[mi][ni][r], SCALE_F, addb[((qbase + r) << 6) + k]);
        }
#pragma unroll
        for (int r=0;r<4;++r){
            float m = fmaxf(fmaxf(s[mi][0][r], s[mi][1][r]), fmaxf(s[mi][2][r], s[mi][3][r]));
            m = fmaxf(m, __shfl_xor(m, 1));
            m = fmaxf(m, __shfl_xor(m, 2));
            m = fmaxf(m, __shfl_xor(m, 4));
            m = fmaxf(m, __shfl_xor(m, 8));
            float sum = 0.f;
#pragma unroll
            for (int ni=0;ni<4;++ni){
                float p = __expf(s[mi][ni][r] - m);
                s[mi][ni][r] = p;
                sum += p;
            }
            sum += __shfl_xor(sum, 1);
            sum += __shfl_xor(sum, 2);
            sum += __shfl_xor(sum, 4);
            sum += __shfl_xor(sum, 8);
            rs[mi][r] = 1.f / sum;
            const int q = qbase + r;
#pragma unroll
            for (int ni=0;ni<4;++ni)
                P_write: ;
#pragma unroll
            for (int ni=0;ni<4;++ni)
                R[q*72 + ni*16 + l15] = f2bs(s[mi][ni][r]);
        }
    }

    // PV: o[64][32] = P @ V
#pragma unroll
    for (int mi=0;mi<4;++mi){ o[mi][0]=zero; o[mi][1]=zero; }
#pragma unroll
    for (int ks=0;ks<2;++ks){
        bf16x8 pa[4], vb[2];
#pragma unroll
        for (int mi=0;mi<4;++mi)
            pa[mi] = *reinterpret_cast<const bf16x8*>(R + (mi*16 + l15)*72 + ks*32 + g*8);
#pragma unroll
        for (int nj=0;nj<2;++nj)
            vb[nj] = *reinterpret_cast<const bf16x8*>(R + 5120 + (nj*16 + l15)*72 + ks*32 + g*8);
#pragma unroll
        for (int mi=0;mi<4;++mi)
#pragma unroll
            for (int nj=0;nj<2;++nj)
                o[mi][nj] = __builtin_amdgcn_mfma_f32_16x16x32_bf16(pa[mi], vb[nj], o[mi][nj], 0,0,0);
    }
#pragma unroll
    for (int mi=0;mi<4;++mi)
#pragma unroll
        for (int nj=0;nj<2;++nj)
#pragma unroll
            for (int r=0;r<4;++r)
                o[mi][nj][r] *= rs[mi][r];
}

__global__ __launch_bounds__(256, 2) void fused_k(
    const float* __restrict__ x, const float* __restrict__ z,
    const short* __restrict__ Wqt, const short* __restrict__ Wkvt,
    const short* __restrict__ Wot,
    const float* __restrict__ bq, const float* __restrict__ bkv,
    const float* __restrict__ bo,
    const float* __restrict__ ADD, float* __restrict__ out){
    __shared__ __align__(16) short lds[4 * WREG];
    const int tid = threadIdx.x, w = tid >> 6, lane = tid & 63;
    const int l15 = lane & 15, g = lane >> 4;
    const int bx = blockIdx.x;
    const int wj = bx & 15, wi = (bx >> 4) & 15, b = bx >> 8;
    const int wiC = (wi > 13) ? wi - 13 : 0;
    const int wjC = (wj > 13) ? wj - 13 : 0;
    short* R = lds + w * WREG;

    int abase[4];
#pragma unroll
    for (int mi=0;mi<4;++mi){
        int p = mi*16 + l15;
        int pr = ((wi << 3) + (p >> 3) + 4) & 127;
        int pc = ((wj << 3) + (p & 7) + 4) & 127;
        abase[mi] = ((((b << 7) + pr) << 7) | pc) << 8;   // *256 floats
    }
    const float* addb0 = ADD + (size_t)(((wiC*3 + wjC)*8 + 2*w) << 12);

    f32x4 o0[4][2], o1[4][2];
    do_head(x, z, Wqt, Wkvt, bq, bkv, addb0,        2*w,     abase, R, l15, g, o0);
    do_head(x, z, Wqt, Wkvt, bq, bkv, addb0 + 4096, 2*w + 1, abase, R, l15, g, o1);

    // att (both heads) -> R[0,4608) pitch 72 (P region, dead)
#pragma unroll
    for (int mi=0;mi<4;++mi)
#pragma unroll
        for (int nj=0;nj<2;++nj)
#pragma unroll
            for (int r=0;r<4;++r){
                const int prow = (mi*16 + g*4 + r) * 72;
                R[prow + nj*16 + l15]      = f2bs(o0[mi][nj][r]);
                R[prow + 32 + nj*16 + l15] = f2bs(o1[mi][nj][r]);
            }
    __syncthreads();

    // O-GEMM: out[64 pix][256] = att[64][256] @ Wot^T + bo ; wave w -> cols w*64..
    f32x4 acc[4][4];
    const f32x4 zero = {0.f,0.f,0.f,0.f};
#pragma unroll
    for (int mi=0;mi<4;++mi)
#pragma unroll
        for (int nj=0;nj<4;++nj) acc[mi][nj] = zero;
#pragma unroll
    for (int kt=0;kt<8;++kt){
        const short* ar = lds + (kt >> 1) * WREG + ((kt & 1) << 5);
        bf16x8 af[4], bfm[4];
#pragma unroll
        for (int mi=0;mi<4;++mi)
            af[mi] = *reinterpret_cast<const bf16x8*>(ar + (mi*16 + l15)*72 + g*8);
#pragma unroll
        for (int nj=0;nj<4;++nj)
            bfm[nj] = *reinterpret_cast<const bf16x8*>(Wot + (size_t)(w*64 + nj*16 + l15)*256 + kt*32 + g*8);
#pragma unroll
        for (int mi=0;mi<4;++mi)
#pragma unroll
            for (int nj=0;nj<4;++nj)
                acc[mi][nj] = __builtin_amdgcn_mfma_f32_16x16x32_bf16(af[mi], bfm[nj], acc[mi][nj], 0,0,0);
    }
#pragma unroll
    for (int nj=0;nj<4;++nj){
        const int col = w*64 + nj*16 + l15;
        const float bv = bo[col];
#pragma unroll
        for (int mi=0;mi<4;++mi)
#pragma unroll
            for (int r=0;r<4;++r){
                const int p = mi*16 + g*4 + r;
                const int pr = ((wi << 3) + (p >> 3) + 4) & 127;
                const int pc = ((wj << 3) + (p & 7) + 4) & 127;
                const size_t gp = ((size_t)((b << 7) + pr) << 7) + pc;
                out[gp * 256 + col] = acc[mi][nj][r] + bv;
            }
    }
}

extern "C" void kernel_launch(void* const* d_in, const int* in_sizes, int n_in,
                              void* d_out, int out_size, void* d_ws, size_t ws_size,
                              hipStream_t stream) {
    const float* x    = (const float*)d_in[0];
    const float* z    = (const float*)d_in[1];
    const float* Wq   = (const float*)d_in[2];
    const float* bq   = (const float*)d_in[3];
    const float* Wkv  = (const float*)d_in[4];
    const float* bkv  = (const float*)d_in[5];
    const float* Wo   = (const float*)d_in[6];
    const float* bo   = (const float*)d_in[7];
    const float* rel  = (const float*)d_in[8];

    char* ws = (char*)d_ws;
    short* Wqt  = (short*)(ws);                    // 128 KiB
    short* Wkvt = (short*)(ws + 131072);           // 256 KiB
    short* Wot  = (short*)(ws + 393216);           // 128 KiB
    float* ADD  = (float*)(ws + 524288);           // 1.125 MiB

    prep_k<<<2176, 256, 0, stream>>>(Wq, Wkv, Wo, rel, Wqt, Wkvt, Wot, ADD);
    fused_k<<<2048, 256, 0, stream>>>(x, z, Wqt, Wkvt, Wot, bq, bkv, bo, ADD, (float*)d_out);
}

// Round 4
// 312.209 us; speedup vs baseline: 4.4682x; 4.4682x over previous
//
#include <hip/hip_runtime.h>
#include <hip/hip_bf16.h>

// Fused Swin shifted-window attention, MI355X gfx950.
// B=8, H=W=128, D=256, NHEAD=8, DK=32, WS=8, NH=NW=16, WSQ=64, SHIFT=4.
// prep_k : weight transposes (bf16) + fused (mask|rel-bias) ADD table.
// fused_k: 1 block = 1 window. Stage x,z windows -> LDS bf16 ONCE.
//          4 waves x 2 heads: QKV proj (A from LDS, B from L2 weights),
//          QK^T -> softmax -> P -> PV. att -> global pixel-major bf16, coalesced.
// ogemm_k: att @ Wo^T + bo -> f32 out. A staged once in LDS, barrier-free K-loop.

typedef __bf16  bf16x8 __attribute__((ext_vector_type(8)));
typedef short   short8 __attribute__((ext_vector_type(8)));
typedef short   short4v __attribute__((ext_vector_type(4)));
typedef float   f32x4  __attribute__((ext_vector_type(4)));

#define SCALE_F 0.17677669529663687f

// fused LDS map (shorts): [0,16896) xs[64][264]; [16896,33792) zs[64][264];
// [33792,...) 4 per-wave regions of WREG:
//   [0,2560) Q[64][40]; [2560,5120) K[64][40]; [5120,7424) V^T[32][72]
//   P/att overlay [0,4608) pitch 72 (Q,K dead after QK^T).
#define ZS   16896
#define PW   33792
#define WREG 7424
#define LDS_TOT (PW + 4*WREG)   // 63488 shorts = 124 KiB

__device__ __forceinline__ short f2bs(float f){
    __hip_bfloat16 h = __float2bfloat16(f);
    return __builtin_bit_cast(short, h);
}
__device__ __forceinline__ short8 cvt8(float4 a, float4 b){
    short8 t;
    t[0]=f2bs(a.x); t[1]=f2bs(a.y); t[2]=f2bs(a.z); t[3]=f2bs(a.w);
    t[4]=f2bs(b.x); t[5]=f2bs(b.y); t[6]=f2bs(b.z); t[7]=f2bs(b.w);
    return t;
}
__device__ __forceinline__ int strip3(int r, int c){
    if (c == 0) return 0;
    if (c == 1) return (r < 4) ? 0 : 1;
    return (r < 4) ? 2 : 0;
}

// ---------------- prep: weight transpose->bf16 + ADD table ------------------
__global__ __launch_bounds__(256) void prep_k(const float* __restrict__ Wq,
                                              const float* __restrict__ Wkv,
                                              const float* __restrict__ Wo,
                                              const float* __restrict__ rel,
                                              short* __restrict__ Wqt,
                                              short* __restrict__ Wkvt,
                                              short* __restrict__ Wot,
                                              float* __restrict__ ADD){
    int i = blockIdx.x * 256 + threadIdx.x;
    if (i < 65536){
        int n = i >> 8, k = i & 255;
        Wqt[i] = f2bs(Wq[k * 256 + n]);
    } else if (i < 196608){
        int j = i - 65536;
        int n = j >> 8, k = j & 255;
        Wkvt[j] = f2bs(Wkv[k * 512 + n]);
    } else if (i < 262144){
        int j = i - 196608;
        int n = j >> 8, k = j & 255;
        Wot[j] = f2bs(Wo[k * 256 + n]);
    } else {
        int j = i - 262144;
        int k = j & 63, q = (j >> 6) & 63, head = (j >> 12) & 7, cls = j >> 15;
        int wiC = cls / 3, wjC = cls - wiC * 3;
        int qr = q >> 3, qc = q & 7, kr = k >> 3, kc = k & 7;
        int lq = strip3(qr, wiC) * 3 + strip3(qc, wjC);
        int lk = strip3(kr, wiC) * 3 + strip3(kc, wjC);
        float pe = rel[((qr - kr + 7) * 15 + (qc - kc + 7)) * 8 + head];
        ADD[j] = (lq != lk) ? -1e9f : pe;
    }
}

// proj, N=32 head-slice: A from staged LDS [64][264], B from global Wt (L2-hot).
// VT=false: dst[pix][col] pitch 40.  VT=true: dst[col][pix] pitch 72.
template<bool VT>
__device__ __forceinline__ void proj32(const short* __restrict__ As,
                                       const short* __restrict__ Wt, int c0,
                                       const float* __restrict__ bias,
                                       short* dst, int l15, int g){
    f32x4 acc[4][2];
    const f32x4 zero = {0.f,0.f,0.f,0.f};
#pragma unroll
    for (int mi=0;mi<4;++mi){ acc[mi][0]=zero; acc[mi][1]=zero; }
#pragma unroll
    for (int kt=0; kt<8; ++kt){
        bf16x8 af[4], bfr[2];
#pragma unroll
        for (int mi=0;mi<4;++mi)
            af[mi] = *reinterpret_cast<const bf16x8*>(As + (mi*16 + l15)*264 + kt*32 + g*8);
#pragma unroll
        for (int nj=0;nj<2;++nj)
            bfr[nj] = *reinterpret_cast<const bf16x8*>(Wt + (size_t)(c0 + nj*16 + l15)*256 + kt*32 + g*8);
#pragma unroll
        for (int mi=0;mi<4;++mi)
#pragma unroll
            for (int nj=0;nj<2;++nj)
                acc[mi][nj] = __builtin_amdgcn_mfma_f32_16x16x32_bf16(af[mi], bfr[nj], acc[mi][nj], 0,0,0);
    }
#pragma unroll
    for (int nj=0;nj<2;++nj){
        float bv = bias[c0 + nj*16 + l15];
        if (VT){
#pragma unroll
            for (int mi=0;mi<4;++mi){
                short4v t;
#pragma unroll
                for (int r=0;r<4;++r) t[r] = f2bs(acc[mi][nj][r] + bv);
                *reinterpret_cast<short4v*>(dst + (nj*16 + l15)*72 + mi*16 + g*4) = t;
            }
        } else {
#pragma unroll
            for (int mi=0;mi<4;++mi)
#pragma unroll
                for (int r=0;r<4;++r)
                    dst[(mi*16 + g*4 + r)*40 + nj*16 + l15] = f2bs(acc[mi][nj][r] + bv);
        }
    }
}

// one head: Q/K/V proj -> S -> softmax -> P -> PV -> o (normalized, in regs)
__device__ __forceinline__ void do_head(const short* __restrict__ xs, const short* __restrict__ zs,
    const short* __restrict__ Wqt, const short* __restrict__ Wkvt,
    const float* __restrict__ bq, const float* __restrict__ bkv,
    const float* __restrict__ addb, int head,
    short* R, int l15, int g, f32x4 (&o)[4][2]){
    const int c0 = head * 32;
    proj32<false>(xs, Wqt,  c0,       bq,  R,        l15, g);   // Q
    proj32<false>(zs, Wkvt, c0,       bkv, R + 2560, l15, g);   // K
    proj32<true >(zs, Wkvt, 256 + c0, bkv, R + 5120, l15, g);   // V^T

    bf16x8 aq[4], bk[4];
#pragma unroll
    for (int mi=0;mi<4;++mi) aq[mi] = *reinterpret_cast<const bf16x8*>(R + (mi*16 + l15)*40 + g*8);
#pragma unroll
    for (int ni=0;ni<4;++ni) bk[ni] = *reinterpret_cast<const bf16x8*>(R + 2560 + (ni*16 + l15)*40 + g*8);
    const f32x4 zero = {0.f,0.f,0.f,0.f};
    f32x4 s[4][4];
#pragma unroll
    for (int mi=0;mi<4;++mi)
#pragma unroll
        for (int ni=0;ni<4;++ni)
            s[mi][ni] = __builtin_amdgcn_mfma_f32_16x16x32_bf16(aq[mi], bk[ni], zero, 0,0,0);

    float rs[4][4];
#pragma unroll
    for (int mi=0;mi<4;++mi){
        const int qbase = mi*16 + g*4;
#pragma unroll
        for (int ni=0;ni<4;++ni){
            const int k = ni*16 + l15;
#pragma unroll
            for (int r=0;r<4;++r)
                s[mi][ni][r] = fmaf(s[mi][ni][r], SCALE_F, addb[((qbase + r) << 6) + k]);
        }
#pragma unroll
        for (int r=0;r<4;++r){
            float m = fmaxf(fmaxf(s[mi][0][r], s[mi][1][r]), fmaxf(s[mi][2][r], s[mi][3][r]));
            m = fmaxf(m, __shfl_xor(m, 1));
            m = fmaxf(m, __shfl_xor(m, 2));
            m = fmaxf(m, __shfl_xor(m, 4));
            m = fmaxf(m, __shfl_xor(m, 8));
            float sum = 0.f;
#pragma unroll
            for (int ni=0;ni<4;++ni){
                float p = __expf(s[mi][ni][r] - m);
                s[mi][ni][r] = p;
                sum += p;
            }
            sum += __shfl_xor(sum, 1);
            sum += __shfl_xor(sum, 2);
            sum += __shfl_xor(sum, 4);
            sum += __shfl_xor(sum, 8);
            rs[mi][r] = 1.f / sum;
            const int q = qbase + r;
#pragma unroll
            for (int ni=0;ni<4;++ni)
                R[q*72 + ni*16 + l15] = f2bs(s[mi][ni][r]);   // P overlay (Q,K dead)
        }
    }

#pragma unroll
    for (int mi=0;mi<4;++mi){ o[mi][0]=zero; o[mi][1]=zero; }
#pragma unroll
    for (int ks=0;ks<2;++ks){
        bf16x8 pa[4], vb[2];
#pragma unroll
        for (int mi=0;mi<4;++mi)
            pa[mi] = *reinterpret_cast<const bf16x8*>(R + (mi*16 + l15)*72 + ks*32 + g*8);
#pragma unroll
        for (int nj=0;nj<2;++nj)
            vb[nj] = *reinterpret_cast<const bf16x8*>(R + 5120 + (nj*16 + l15)*72 + ks*32 + g*8);
#pragma unroll
        for (int mi=0;mi<4;++mi)
#pragma unroll
            for (int nj=0;nj<2;++nj)
                o[mi][nj] = __builtin_amdgcn_mfma_f32_16x16x32_bf16(pa[mi], vb[nj], o[mi][nj], 0,0,0);
    }
#pragma unroll
    for (int mi=0;mi<4;++mi)
#pragma unroll
        for (int nj=0;nj<2;++nj)
#pragma unroll
            for (int r=0;r<4;++r)
                o[mi][nj][r] *= rs[mi][r];
}

__global__ __launch_bounds__(256, 2) void fused_k(
    const float* __restrict__ x, const float* __restrict__ z,
    const short* __restrict__ Wqt, const short* __restrict__ Wkvt,
    const float* __restrict__ bq, const float* __restrict__ bkv,
    const float* __restrict__ ADD, short* __restrict__ attG){
    __shared__ __align__(16) short lds[LDS_TOT];
    const int tid = threadIdx.x, w = tid >> 6, lane = tid & 63;
    const int l15 = lane & 15, g = lane >> 4;
    const int bx = blockIdx.x;
    const int wj = bx & 15, wi = (bx >> 4) & 15, b = bx >> 8;
    const int wiC = (wi > 13) ? wi - 13 : 0;
    const int wjC = (wj > 13) ? wj - 13 : 0;

    // ---- stage x,z windows -> LDS bf16 [64][264] (read once from HBM) ----
    {
        const int p = tid >> 2, qtr = tid & 3;
        const int pr = ((wi << 3) + (p >> 3) + 4) & 127;
        const int pc = ((wj << 3) + (p & 7) + 4) & 127;
        const size_t gbase = (((((size_t)b << 7) | pr) << 7) | pc) << 8;  // float idx
        const float4* xp = reinterpret_cast<const float4*>(x + gbase + qtr * 64);
        const float4* zp = reinterpret_cast<const float4*>(z + gbase + qtr * 64);
        float4 xv[16];
#pragma unroll
        for (int i=0;i<16;++i) xv[i] = xp[i];
        short* xd = lds + p*264 + qtr*64;
#pragma unroll
        for (int j=0;j<8;++j)
            *reinterpret_cast<short8*>(xd + j*8) = cvt8(xv[2*j], xv[2*j+1]);
        float4 zv[16];
#pragma unroll
        for (int i=0;i<16;++i) zv[i] = zp[i];
        short* zd = lds + ZS + p*264 + qtr*64;
#pragma unroll
        for (int j=0;j<8;++j)
            *reinterpret_cast<short8*>(zd + j*8) = cvt8(zv[2*j], zv[2*j+1]);
    }
    __syncthreads();

    short* R = lds + PW + w * WREG;
    const float* addb0 = ADD + (size_t)(((wiC*3 + wjC)*8 + 2*w) << 12);

    f32x4 o0[4][2], o1[4][2];
    do_head(lds, lds + ZS, Wqt, Wkvt, bq, bkv, addb0,        2*w,     R, l15, g, o0);
    do_head(lds, lds + ZS, Wqt, Wkvt, bq, bkv, addb0 + 4096, 2*w + 1, R, l15, g, o1);

    // att (both heads) -> R[0,4608) pitch 72 (P region dead)
#pragma unroll
    for (int mi=0;mi<4;++mi)
#pragma unroll
        for (int nj=0;nj<2;++nj)
#pragma unroll
            for (int r=0;r<4;++r){
                const int prow = (mi*16 + g*4 + r) * 72;
                R[prow + nj*16 + l15]      = f2bs(o0[mi][nj][r]);
                R[prow + 32 + nj*16 + l15] = f2bs(o1[mi][nj][r]);
            }
    __syncthreads();

    // ---- cooperative coalesced att write: pixel-major bf16 [gp][256] ----
    const short* base = lds + PW;
#pragma unroll
    for (int u = tid; u < 2048; u += 256){
        const int p2 = u >> 5, c5 = u & 31;
        const int head = c5 >> 2;
        const short* src = base + (head >> 1)*WREG + p2*72 + (head & 1)*32 + (c5 & 3)*8;
        const int pr = ((wi << 3) + (p2 >> 3) + 4) & 127;
        const int pc = ((wj << 3) + (p2 & 7) + 4) & 127;
        const size_t gp = ((((size_t)b << 7) | pr) << 7) | pc;
        *reinterpret_cast<short8*>(attG + gp*256 + c5*8) = *reinterpret_cast<const short8*>(src);
    }
}

// ---------------- O-GEMM: out[131072][256] = att @ Wot^T + bo (f32) --------
__global__ __launch_bounds__(256, 4) void ogemm_k(const short* __restrict__ att,
                                                  const short* __restrict__ Wot,
                                                  const float* __restrict__ bo,
                                                  float* __restrict__ out){
    __shared__ __align__(16) short As[64 * 264];
    const int tid = threadIdx.x, w = tid >> 6, lane = tid & 63;
    const int l15 = lane & 15, g = lane >> 4;
    const int m0 = blockIdx.x * 64;

#pragma unroll
    for (int i=0;i<8;++i){
        const int u = tid + i*256;
        const int p = u >> 5, c = u & 31;
        *reinterpret_cast<short8*>(&As[p*264 + c*8]) =
            *reinterpret_cast<const short8*>(att + (size_t)(m0 + p)*256 + c*8);
    }
    __syncthreads();

    f32x4 acc[4][4];
    const f32x4 zero = {0.f,0.f,0.f,0.f};
#pragma unroll
    for (int mi=0;mi<4;++mi)
#pragma unroll
        for (int nj=0;nj<4;++nj) acc[mi][nj] = zero;
#pragma unroll
    for (int kt=0;kt<8;++kt){
        bf16x8 af[4], bfm[4];
#pragma unroll
        for (int mi=0;mi<4;++mi)
            af[mi] = *reinterpret_cast<const bf16x8*>(&As[(mi*16 + l15)*264 + kt*32 + g*8]);
#pragma unroll
        for (int nj=0;nj<4;++nj)
            bfm[nj] = *reinterpret_cast<const bf16x8*>(Wot + (size_t)(w*64 + nj*16 + l15)*256 + kt*32 + g*8);
#pragma unroll
        for (int mi=0;mi<4;++mi)
#pragma unroll
            for (int nj=0;nj<4;++nj)
                acc[mi][nj] = __builtin_amdgcn_mfma_f32_16x16x32_bf16(af[mi], bfm[nj], acc[mi][nj], 0,0,0);
    }
#pragma unroll
    for (int nj=0;nj<4;++nj){
        const int col = w*64 + nj*16 + l15;
        const float bv = bo[col];
#pragma unroll
        for (int mi=0;mi<4;++mi)
#pragma unroll
            for (int r=0;r<4;++r)
                out[(size_t)(m0 + mi*16 + g*4 + r)*256 + col] = acc[mi][nj][r] + bv;
    }
}

extern "C" void kernel_launch(void* const* d_in, const int* in_sizes, int n_in,
                              void* d_out, int out_size, void* d_ws, size_t ws_size,
                              hipStream_t stream) {
    const float* x    = (const float*)d_in[0];
    const float* z    = (const float*)d_in[1];
    const float* Wq   = (const float*)d_in[2];
    const float* bq   = (const float*)d_in[3];
    const float* Wkv  = (const float*)d_in[4];
    const float* bkv  = (const float*)d_in[5];
    const float* Wo   = (const float*)d_in[6];
    const float* bo   = (const float*)d_in[7];
    const float* rel  = (const float*)d_in[8];

    char* ws = (char*)d_ws;
    short* Wqt  = (short*)(ws);                    // 128 KiB
    short* Wkvt = (short*)(ws + 131072);           // 256 KiB
    short* Wot  = (short*)(ws + 393216);           // 128 KiB
    float* ADD  = (float*)(ws + 524288);           // 1.125 MiB
    short* attG = (short*)(ws + 2097152);          // 64 MiB

    prep_k<<<2176, 256, 0, stream>>>(Wq, Wkv, Wo, rel, Wqt, Wkvt, Wot, ADD);
    fused_k<<<2048, 256, 0, stream>>>(x, z, Wqt, Wkvt, bq, bkv, ADD, attG);
    ogemm_k<<<2048, 256, 0, stream>>>(attG, Wot, bo, (float*)d_out);
}

// Round 5
// 255.308 us; speedup vs baseline: 5.4640x; 1.2229x over previous
//
#include <hip/hip_runtime.h>
#include <hip/hip_bf16.h>

// Fully-fused Swin shifted-window attention, MI355X gfx950.
// B=8, H=W=128, D=256, NHEAD=8, DK=32, WS=8, NH=NW=16, WSQ=64, SHIFT=4.
// prep_k : weight transposes (bf16) + fused (mask|rel-bias) ADD table.
// fused_k: 1 block = 1 window, 512 threads = 8 waves, 1 head/wave.
//   stage x,z windows -> LDS bf16 once; per wave: Q,K proj -> barrier ->
//   V^T proj (overlays dead xs) -> QK^T -> softmax -> P (overlays Q/K) ->
//   PV -> att (overlays P) -> barrier -> in-block O-GEMM -> f32 out direct.

typedef __bf16  bf16x8 __attribute__((ext_vector_type(8)));
typedef short   short8 __attribute__((ext_vector_type(8)));
typedef float   f32x4  __attribute__((ext_vector_type(4)));

#define SCALE_F 0.17677669529663687f

// LDS map (shorts):
//  [0,16896)      xs[64][264]; after barrier: 8x V^T[32][66] at w*2112
//  [16896,33792)  zs[64][264]
//  [33792,74752)  8 per-wave regions of 5120:
//     Q[64][40] @0, K[64][40] @2560; P[64][72] overlay @0; att[64][40] overlay @0
#define ZS   16896
#define WB   33792
#define WSZ  5120
#define VPITCH 66
#define LDS_TOT 74752   // shorts = 146 KiB

__device__ __forceinline__ short f2bs(float f){
    __hip_bfloat16 h = __float2bfloat16(f);
    return __builtin_bit_cast(short, h);
}
__device__ __forceinline__ short8 cvt8(float4 a, float4 b){
    short8 t;
    t[0]=f2bs(a.x); t[1]=f2bs(a.y); t[2]=f2bs(a.z); t[3]=f2bs(a.w);
    t[4]=f2bs(b.x); t[5]=f2bs(b.y); t[6]=f2bs(b.z); t[7]=f2bs(b.w);
    return t;
}
__device__ __forceinline__ int strip3(int r, int c){
    if (c == 0) return 0;
    if (c == 1) return (r < 4) ? 0 : 1;
    return (r < 4) ? 2 : 0;
}

// ---------------- prep: weight transpose->bf16 + ADD table ------------------
__global__ __launch_bounds__(256) void prep_k(const float* __restrict__ Wq,
                                              const float* __restrict__ Wkv,
                                              const float* __restrict__ Wo,
                                              const float* __restrict__ rel,
                                              short* __restrict__ Wqt,
                                              short* __restrict__ Wkvt,
                                              short* __restrict__ Wot,
                                              float* __restrict__ ADD){
    int i = blockIdx.x * 256 + threadIdx.x;
    if (i < 65536){
        int n = i >> 8, k = i & 255;
        Wqt[i] = f2bs(Wq[k * 256 + n]);
    } else if (i < 196608){
        int j = i - 65536;
        int n = j >> 8, k = j & 255;
        Wkvt[j] = f2bs(Wkv[k * 512 + n]);
    } else if (i < 262144){
        int j = i - 196608;
        int n = j >> 8, k = j & 255;
        Wot[j] = f2bs(Wo[k * 256 + n]);
    } else {
        int j = i - 262144;
        int k = j & 63, q = (j >> 6) & 63, head = (j >> 12) & 7, cls = j >> 15;
        int wiC = cls / 3, wjC = cls - wiC * 3;
        int qr = q >> 3, qc = q & 7, kr = k >> 3, kc = k & 7;
        int lq = strip3(qr, wiC) * 3 + strip3(qc, wjC);
        int lk = strip3(kr, wiC) * 3 + strip3(kc, wjC);
        float pe = rel[((qr - kr + 7) * 15 + (qc - kc + 7)) * 8 + head];
        ADD[j] = (lq != lk) ? -1e9f : pe;
    }
}

// projection, N=32 head-slice. A from LDS [64][264] bf16, B from global Wt.
// Q/K store: dst[pix][col'] pitch 40.
__device__ __forceinline__ void projQK(const short* __restrict__ As,
                                       const short* __restrict__ Wt, int c0,
                                       const float* __restrict__ bias,
                                       short* __restrict__ dst, int l15, int g){
    f32x4 acc[4][2];
    const f32x4 zero = {0.f,0.f,0.f,0.f};
#pragma unroll
    for (int mi=0;mi<4;++mi){ acc[mi][0]=zero; acc[mi][1]=zero; }
#pragma unroll
    for (int kt=0; kt<8; ++kt){
        bf16x8 af[4], bfr[2];
#pragma unroll
        for (int mi=0;mi<4;++mi)
            af[mi] = *reinterpret_cast<const bf16x8*>(As + (mi*16 + l15)*264 + kt*32 + g*8);
#pragma unroll
        for (int nj=0;nj<2;++nj)
            bfr[nj] = *reinterpret_cast<const bf16x8*>(Wt + (size_t)(c0 + nj*16 + l15)*256 + kt*32 + g*8);
#pragma unroll
        for (int mi=0;mi<4;++mi)
#pragma unroll
            for (int nj=0;nj<2;++nj)
                acc[mi][nj] = __builtin_amdgcn_mfma_f32_16x16x32_bf16(af[mi], bfr[nj], acc[mi][nj], 0,0,0);
    }
#pragma unroll
    for (int nj=0;nj<2;++nj){
        float bv = bias[c0 + nj*16 + l15];
#pragma unroll
        for (int mi=0;mi<4;++mi)
#pragma unroll
            for (int r=0;r<4;++r)
                dst[(mi*16 + g*4 + r)*40 + nj*16 + l15] = f2bs(acc[mi][nj][r] + bv);
    }
}
// V^T store: dst[col'][pix] pitch 66 (element stores; row stride 33 dwords = conflict-free)
__device__ __forceinline__ void projV(const short* __restrict__ As,
                                      const short* __restrict__ Wt, int c0,
                                      const float* __restrict__ bias,
                                      short* __restrict__ dst, int l15, int g){
    f32x4 acc[4][2];
    const f32x4 zero = {0.f,0.f,0.f,0.f};
#pragma unroll
    for (int mi=0;mi<4;++mi){ acc[mi][0]=zero; acc[mi][1]=zero; }
#pragma unroll
    for (int kt=0; kt<8; ++kt){
        bf16x8 af[4], bfr[2];
#pragma unroll
        for (int mi=0;mi<4;++mi)
            af[mi] = *reinterpret_cast<const bf16x8*>(As + (mi*16 + l15)*264 + kt*32 + g*8);
#pragma unroll
        for (int nj=0;nj<2;++nj)
            bfr[nj] = *reinterpret_cast<const bf16x8*>(Wt + (size_t)(c0 + nj*16 + l15)*256 + kt*32 + g*8);
#pragma unroll
        for (int mi=0;mi<4;++mi)
#pragma unroll
            for (int nj=0;nj<2;++nj)
                acc[mi][nj] = __builtin_amdgcn_mfma_f32_16x16x32_bf16(af[mi], bfr[nj], acc[mi][nj], 0,0,0);
    }
#pragma unroll
    for (int nj=0;nj<2;++nj){
        float bv = bias[c0 + nj*16 + l15];
#pragma unroll
        for (int mi=0;mi<4;++mi)
#pragma unroll
            for (int r=0;r<4;++r)
                dst[(nj*16 + l15)*VPITCH + mi*16 + g*4 + r] = f2bs(acc[mi][nj][r] + bv);
    }
}

__global__ __launch_bounds__(512, 2) void fused_k(
    const float* __restrict__ x, const float* __restrict__ z,
    const short* __restrict__ Wqt, const short* __restrict__ Wkvt,
    const short* __restrict__ Wot,
    const float* __restrict__ bq, const float* __restrict__ bkv,
    const float* __restrict__ bo,
    const float* __restrict__ ADD, float* __restrict__ out){
    __shared__ __align__(16) short lds[LDS_TOT];
    const int tid = threadIdx.x, w = tid >> 6, lane = tid & 63;
    const int l15 = lane & 15, g = lane >> 4;
    const int bx = blockIdx.x;
    const int wj = bx & 15, wi = (bx >> 4) & 15, b = bx >> 8;
    const int wiC = (wi > 13) ? wi - 13 : 0;
    const int wjC = (wj > 13) ? wj - 13 : 0;

    // ---- stage x,z windows -> LDS bf16 [64][264], read once from HBM ----
#pragma unroll
    for (int i=0;i<4;++i){
        const int u = tid + i*512;           // [0,2048) : (pixel, 8-float chunk)
        const int p = u >> 5, c8 = u & 31;
        const int pr = ((wi << 3) + (p >> 3) + 4) & 127;
        const int pc = ((wj << 3) + (p & 7) + 4) & 127;
        const size_t gidx = ((((((size_t)b << 7) | pr) << 7) | pc) << 8) + c8*8;
        const float4* xp = reinterpret_cast<const float4*>(x + gidx);
        float4 a0 = xp[0], a1 = xp[1];
        *reinterpret_cast<short8*>(lds + p*264 + c8*8) = cvt8(a0, a1);
        const float4* zp = reinterpret_cast<const float4*>(z + gidx);
        float4 b0 = zp[0], b1 = zp[1];
        *reinterpret_cast<short8*>(lds + ZS + p*264 + c8*8) = cvt8(b0, b1);
    }
    __syncthreads();

    short* R  = lds + WB + w*WSZ;     // Q @0 p40, K @2560 p40; P/att overlay @0
    short* VL = lds + w*2112;         // V^T [32][66] overlays dead xs
    const int c0 = w*32;

    projQK(lds,      Wqt,  c0, bq,  R,        l15, g);   // Q
    projQK(lds + ZS, Wkvt, c0, bkv, R + 2560, l15, g);   // K
    __syncthreads();                                     // xs dead everywhere
    projV (lds + ZS, Wkvt, 256 + c0, bkv, VL, l15, g);   // V^T -> xs overlay

    // ---- QK^T ----
    bf16x8 aq[4], bk[4];
#pragma unroll
    for (int mi=0;mi<4;++mi) aq[mi] = *reinterpret_cast<const bf16x8*>(R + (mi*16 + l15)*40 + g*8);
#pragma unroll
    for (int ni=0;ni<4;++ni) bk[ni] = *reinterpret_cast<const bf16x8*>(R + 2560 + (ni*16 + l15)*40 + g*8);
    const f32x4 zero = {0.f,0.f,0.f,0.f};
    f32x4 s[4][4];
#pragma unroll
    for (int mi=0;mi<4;++mi)
#pragma unroll
        for (int ni=0;ni<4;++ni)
            s[mi][ni] = __builtin_amdgcn_mfma_f32_16x16x32_bf16(aq[mi], bk[ni], zero, 0,0,0);

    // ---- scale + (mask|bias), wave-parallel softmax, P -> R pitch 72 ----
    const float* addb = ADD + (size_t)(((wiC*3 + wjC)*8 + w) << 12);
    float rs[4][4];
#pragma unroll
    for (int mi=0;mi<4;++mi){
        const int qbase = mi*16 + g*4;
#pragma unroll
        for (int ni=0;ni<4;++ni){
            const int k = ni*16 + l15;
#pragma unroll
            for (int r=0;r<4;++r)
                s[mi][ni][r] = fmaf(s[mi][ni][r], SCALE_F, addb[((qbase + r) << 6) + k]);
        }
#pragma unroll
        for (int r=0;r<4;++r){
            float m = fmaxf(fmaxf(s[mi][0][r], s[mi][1][r]), fmaxf(s[mi][2][r], s[mi][3][r]));
            m = fmaxf(m, __shfl_xor(m, 1));
            m = fmaxf(m, __shfl_xor(m, 2));
            m = fmaxf(m, __shfl_xor(m, 4));
            m = fmaxf(m, __shfl_xor(m, 8));
            float sum = 0.f;
#pragma unroll
            for (int ni=0;ni<4;++ni){
                float p = __expf(s[mi][ni][r] - m);
                s[mi][ni][r] = p;
                sum += p;
            }
            sum += __shfl_xor(sum, 1);
            sum += __shfl_xor(sum, 2);
            sum += __shfl_xor(sum, 4);
            sum += __shfl_xor(sum, 8);
            rs[mi][r] = 1.f / sum;
            const int q = qbase + r;
#pragma unroll
            for (int ni=0;ni<4;++ni)
                R[q*72 + ni*16 + l15] = f2bs(s[mi][ni][r]);
        }
    }

    // ---- PV: o[64][32] = P @ V ----
    f32x4 o[4][2];
#pragma unroll
    for (int mi=0;mi<4;++mi){ o[mi][0]=zero; o[mi][1]=zero; }
#pragma unroll
    for (int ks=0;ks<2;++ks){
        bf16x8 pa[4], vb[2];
#pragma unroll
        for (int mi=0;mi<4;++mi)
            pa[mi] = *reinterpret_cast<const bf16x8*>(R + (mi*16 + l15)*72 + ks*32 + g*8);
#pragma unroll
        for (int nj=0;nj<2;++nj){
            short8 t;
#pragma unroll
            for (int j=0;j<8;++j)
                t[j] = VL[(nj*16 + l15)*VPITCH + ks*32 + g*8 + j];
            vb[nj] = __builtin_bit_cast(bf16x8, t);
        }
#pragma unroll
        for (int mi=0;mi<4;++mi)
#pragma unroll
            for (int nj=0;nj<2;++nj)
                o[mi][nj] = __builtin_amdgcn_mfma_f32_16x16x32_bf16(pa[mi], vb[nj], o[mi][nj], 0,0,0);
    }

    // ---- att (normalized bf16) -> R pitch 40 (P dead) ----
#pragma unroll
    for (int mi=0;mi<4;++mi)
#pragma unroll
        for (int nj=0;nj<2;++nj)
#pragma unroll
            for (int r=0;r<4;++r)
                R[(mi*16 + g*4 + r)*40 + nj*16 + l15] = f2bs(o[mi][nj][r] * rs[mi][r]);
    __syncthreads();

    // ---- in-block O-GEMM: out[64][256] = att[64][256] @ Wot^T + bo --------
    f32x4 acc[4][2];
#pragma unroll
    for (int mi=0;mi<4;++mi){ acc[mi][0]=zero; acc[mi][1]=zero; }
#pragma unroll
    for (int kt=0;kt<8;++kt){
        const short* areg = lds + WB + kt*WSZ;   // wave kt's att (head kt)
        bf16x8 af[4], bfm[2];
#pragma unroll
        for (int mi=0;mi<4;++mi)
            af[mi] = *reinterpret_cast<const bf16x8*>(areg + (mi*16 + l15)*40 + g*8);
#pragma unroll
        for (int nj=0;nj<2;++nj)
            bfm[nj] = *reinterpret_cast<const bf16x8*>(Wot + (size_t)(w*32 + nj*16 + l15)*256 + kt*32 + g*8);
#pragma unroll
        for (int mi=0;mi<4;++mi)
#pragma unroll
            for (int nj=0;nj<2;++nj)
                acc[mi][nj] = __builtin_amdgcn_mfma_f32_16x16x32_bf16(af[mi], bfm[nj], acc[mi][nj], 0,0,0);
    }
#pragma unroll
    for (int nj=0;nj<2;++nj){
        const int col = w*32 + nj*16 + l15;
        const float bv = bo[col];
#pragma unroll
        for (int mi=0;mi<4;++mi)
#pragma unroll
            for (int r=0;r<4;++r){
                const int p = mi*16 + g*4 + r;
                const int pr = ((wi << 3) + (p >> 3) + 4) & 127;
                const int pc = ((wj << 3) + (p & 7) + 4) & 127;
                const size_t gp = ((((size_t)b << 7) | pr) << 7) | pc;
                out[gp * 256 + col] = acc[mi][nj][r] + bv;
            }
    }
}

extern "C" void kernel_launch(void* const* d_in, const int* in_sizes, int n_in,
                              void* d_out, int out_size, void* d_ws, size_t ws_size,
                              hipStream_t stream) {
    const float* x    = (const float*)d_in[0];
    const float* z    = (const float*)d_in[1];
    const float* Wq   = (const float*)d_in[2];
    const float* bq   = (const float*)d_in[3];
    const float* Wkv  = (const float*)d_in[4];
    const float* bkv  = (const float*)d_in[5];
    const float* Wo   = (const float*)d_in[6];
    const float* bo   = (const float*)d_in[7];
    const float* rel  = (const float*)d_in[8];

    char* ws = (char*)d_ws;
    short* Wqt  = (short*)(ws);                    // 128 KiB
    short* Wkvt = (short*)(ws + 131072);           // 256 KiB
    short* Wot  = (short*)(ws + 393216);           // 128 KiB
    float* ADD  = (float*)(ws + 524288);           // 1.125 MiB

    prep_k<<<2176, 256, 0, stream>>>(Wq, Wkv, Wo, rel, Wqt, Wkvt, Wot, ADD);
    fused_k<<<2048, 512, 0, stream>>>(x, z, Wqt, Wkvt, Wot, bq, bkv, bo, ADD, (float*)d_out);
}

// Round 6
// 252.051 us; speedup vs baseline: 5.5346x; 1.0129x over previous
//
#include <hip/hip_runtime.h>
#include <hip/hip_bf16.h>

// Fully-fused Swin shifted-window attention, MI355X gfx950.
// B=8, H=W=128, D=256, NHEAD=8, DK=32, WS=8, NH=NW=16, WSQ=64, SHIFT=4.
// fused_k: 1 block = 1 window, 512 threads = 8 waves, 1 head/wave.
//   stage x,z -> LDS bf16 once; per wave: Q,K proj (weights preloaded in regs)
//   -> barrier -> V^T proj into XOR-swizzled pitch-64 region (overlays dead xs)
//   -> QK^T -> softmax -> P -> PV (b128 swizzled V reads) -> att -> barrier
//   -> in-block O-GEMM (weights preloaded) -> f32 out.

typedef __bf16  bf16x8 __attribute__((ext_vector_type(8)));
typedef short   short8 __attribute__((ext_vector_type(8)));
typedef float   f32x4  __attribute__((ext_vector_type(4)));

#define SCALE_F 0.17677669529663687f

// LDS map (shorts):
//  [0,16896)      xs[64][264]; after barrier: 8x V^T[32][64] (XOR-swizzled) at w*2048
//  [16896,33792)  zs[64][264]
//  [33792,74752)  8 per-wave regions of 5120:
//     Q[64][40] @0, K[64][40] @2560; P[64][72] overlay @0; att[64][40] overlay @0
#define ZS   16896
#define WB   33792
#define WSZ  5120
#define LDS_TOT 74752   // shorts = 146 KiB

__device__ __forceinline__ short f2bs(float f){
    __hip_bfloat16 h = __float2bfloat16(f);
    return __builtin_bit_cast(short, h);
}
__device__ __forceinline__ short8 cvt8(float4 a, float4 b){
    short8 t;
    t[0]=f2bs(a.x); t[1]=f2bs(a.y); t[2]=f2bs(a.z); t[3]=f2bs(a.w);
    t[4]=f2bs(b.x); t[5]=f2bs(b.y); t[6]=f2bs(b.z); t[7]=f2bs(b.w);
    return t;
}
__device__ __forceinline__ int strip3(int r, int c){
    if (c == 0) return 0;
    if (c == 1) return (r < 4) ? 0 : 1;
    return (r < 4) ? 2 : 0;
}

// ---------------- prep: weight transpose->bf16 + ADD table ------------------
__global__ __launch_bounds__(256) void prep_k(const float* __restrict__ Wq,
                                              const float* __restrict__ Wkv,
                                              const float* __restrict__ Wo,
                                              const float* __restrict__ rel,
                                              short* __restrict__ Wqt,
                                              short* __restrict__ Wkvt,
                                              short* __restrict__ Wot,
                                              float* __restrict__ ADD){
    int i = blockIdx.x * 256 + threadIdx.x;
    if (i < 65536){
        int n = i >> 8, k = i & 255;
        Wqt[i] = f2bs(Wq[k * 256 + n]);
    } else if (i < 196608){
        int j = i - 65536;
        int n = j >> 8, k = j & 255;
        Wkvt[j] = f2bs(Wkv[k * 512 + n]);
    } else if (i < 262144){
        int j = i - 196608;
        int n = j >> 8, k = j & 255;
        Wot[j] = f2bs(Wo[k * 256 + n]);
    } else {
        int j = i - 262144;
        int k = j & 63, q = (j >> 6) & 63, head = (j >> 12) & 7, cls = j >> 15;
        int wiC = cls / 3, wjC = cls - wiC * 3;
        int qr = q >> 3, qc = q & 7, kr = k >> 3, kc = k & 7;
        int lq = strip3(qr, wiC) * 3 + strip3(qc, wjC);
        int lk = strip3(kr, wiC) * 3 + strip3(kc, wjC);
        float pe = rel[((qr - kr + 7) * 15 + (qc - kc + 7)) * 8 + head];
        ADD[j] = (lq != lk) ? -1e9f : pe;
    }
}

__global__ __launch_bounds__(512, 2) void fused_k(
    const float* __restrict__ x, const float* __restrict__ z,
    const short* __restrict__ Wqt, const short* __restrict__ Wkvt,
    const short* __restrict__ Wot,
    const float* __restrict__ bq, const float* __restrict__ bkv,
    const float* __restrict__ bo,
    const float* __restrict__ ADD, float* __restrict__ out){
    __shared__ __align__(16) short lds[LDS_TOT];
    const int tid = threadIdx.x, w = tid >> 6, lane = tid & 63;
    const int l15 = lane & 15, g = lane >> 4;
    const int bx = blockIdx.x;
    const int wj = bx & 15, wi = (bx >> 4) & 15, b = bx >> 8;
    const int wiC = (wi > 13) ? wi - 13 : 0;
    const int wjC = (wj > 13) ? wj - 13 : 0;
    const f32x4 zero = {0.f,0.f,0.f,0.f};

    // ---- stage x,z windows -> LDS bf16 [64][264], read once from HBM ----
#pragma unroll
    for (int i=0;i<4;++i){
        const int u = tid + i*512;
        const int p = u >> 5, c8 = u & 31;
        const int pr = ((wi << 3) + (p >> 3) + 4) & 127;
        const int pc = ((wj << 3) + (p & 7) + 4) & 127;
        const size_t gidx = ((((((size_t)b << 7) | pr) << 7) | pc) << 8) + c8*8;
        const float4* xp = reinterpret_cast<const float4*>(x + gidx);
        float4 a0 = xp[0], a1 = xp[1];
        *reinterpret_cast<short8*>(lds + p*264 + c8*8) = cvt8(a0, a1);
        const float4* zp = reinterpret_cast<const float4*>(z + gidx);
        float4 b0 = zp[0], b1 = zp[1];
        *reinterpret_cast<short8*>(lds + ZS + p*264 + c8*8) = cvt8(b0, b1);
    }
    __syncthreads();

    short* R  = lds + WB + w*WSZ;     // Q @0 p40, K @2560 p40; P/att overlay @0
    short* VL = lds + w*2048;         // V^T [32][64] swizzled, overlays dead xs
    const int c0 = w*32;

    // ---- Q projection: weights preloaded, then {ds_read, MFMA} loop ----
    {
        bf16x8 wf[8][2];
#pragma unroll
        for (int kt=0;kt<8;++kt)
#pragma unroll
            for (int nj=0;nj<2;++nj)
                wf[kt][nj] = *reinterpret_cast<const bf16x8*>(Wqt + (size_t)(c0 + nj*16 + l15)*256 + kt*32 + g*8);
        f32x4 acc[4][2];
#pragma unroll
        for (int mi=0;mi<4;++mi){ acc[mi][0]=zero; acc[mi][1]=zero; }
#pragma unroll
        for (int kt=0;kt<8;++kt){
            bf16x8 af[4];
#pragma unroll
            for (int mi=0;mi<4;++mi)
                af[mi] = *reinterpret_cast<const bf16x8*>(lds + (mi*16 + l15)*264 + kt*32 + g*8);
#pragma unroll
            for (int mi=0;mi<4;++mi)
#pragma unroll
                for (int nj=0;nj<2;++nj)
                    acc[mi][nj] = __builtin_amdgcn_mfma_f32_16x16x32_bf16(af[mi], wf[kt][nj], acc[mi][nj], 0,0,0);
        }
#pragma unroll
        for (int nj=0;nj<2;++nj){
            float bv = bq[c0 + nj*16 + l15];
#pragma unroll
            for (int mi=0;mi<4;++mi)
#pragma unroll
                for (int r=0;r<4;++r)
                    R[(mi*16 + g*4 + r)*40 + nj*16 + l15] = f2bs(acc[mi][nj][r] + bv);
        }
    }
    // ---- K projection ----
    {
        bf16x8 wf[8][2];
#pragma unroll
        for (int kt=0;kt<8;++kt)
#pragma unroll
            for (int nj=0;nj<2;++nj)
                wf[kt][nj] = *reinterpret_cast<const bf16x8*>(Wkvt + (size_t)(c0 + nj*16 + l15)*256 + kt*32 + g*8);
        f32x4 acc[4][2];
#pragma unroll
        for (int mi=0;mi<4;++mi){ acc[mi][0]=zero; acc[mi][1]=zero; }
#pragma unroll
        for (int kt=0;kt<8;++kt){
            bf16x8 af[4];
#pragma unroll
            for (int mi=0;mi<4;++mi)
                af[mi] = *reinterpret_cast<const bf16x8*>(lds + ZS + (mi*16 + l15)*264 + kt*32 + g*8);
#pragma unroll
            for (int mi=0;mi<4;++mi)
#pragma unroll
                for (int nj=0;nj<2;++nj)
                    acc[mi][nj] = __builtin_amdgcn_mfma_f32_16x16x32_bf16(af[mi], wf[kt][nj], acc[mi][nj], 0,0,0);
        }
#pragma unroll
        for (int nj=0;nj<2;++nj){
            float bv = bkv[c0 + nj*16 + l15];
#pragma unroll
            for (int mi=0;mi<4;++mi)
#pragma unroll
                for (int r=0;r<4;++r)
                    R[2560 + (mi*16 + g*4 + r)*40 + nj*16 + l15] = f2bs(acc[mi][nj][r] + bv);
        }
    }
    __syncthreads();   // xs reads done everywhere -> V^T may overlay
    // ---- V projection -> VL[col][pix] pitch 64, XOR-swizzled ----
    {
        bf16x8 wf[8][2];
#pragma unroll
        for (int kt=0;kt<8;++kt)
#pragma unroll
            for (int nj=0;nj<2;++nj)
                wf[kt][nj] = *reinterpret_cast<const bf16x8*>(Wkvt + (size_t)(256 + c0 + nj*16 + l15)*256 + kt*32 + g*8);
        f32x4 acc[4][2];
#pragma unroll
        for (int mi=0;mi<4;++mi){ acc[mi][0]=zero; acc[mi][1]=zero; }
#pragma unroll
        for (int kt=0;kt<8;++kt){
            bf16x8 af[4];
#pragma unroll
            for (int mi=0;mi<4;++mi)
                af[mi] = *reinterpret_cast<const bf16x8*>(lds + ZS + (mi*16 + l15)*264 + kt*32 + g*8);
#pragma unroll
            for (int mi=0;mi<4;++mi)
#pragma unroll
                for (int nj=0;nj<2;++nj)
                    acc[mi][nj] = __builtin_amdgcn_mfma_f32_16x16x32_bf16(af[mi], wf[kt][nj], acc[mi][nj], 0,0,0);
        }
        const int sw = (l15 & 7) << 3;
#pragma unroll
        for (int nj=0;nj<2;++nj){
            float bv = bkv[256 + c0 + nj*16 + l15];
            const int colb = (nj*16 + l15) * 64;
#pragma unroll
            for (int mi=0;mi<4;++mi)
#pragma unroll
                for (int r=0;r<4;++r)
                    VL[(colb + mi*16 + g*4 + r) ^ sw] = f2bs(acc[mi][nj][r] + bv);
        }
    }

    // ---- QK^T ----
    bf16x8 aq[4], bk[4];
#pragma unroll
    for (int mi=0;mi<4;++mi) aq[mi] = *reinterpret_cast<const bf16x8*>(R + (mi*16 + l15)*40 + g*8);
#pragma unroll
    for (int ni=0;ni<4;++ni) bk[ni] = *reinterpret_cast<const bf16x8*>(R + 2560 + (ni*16 + l15)*40 + g*8);
    f32x4 s[4][4];
#pragma unroll
    for (int mi=0;mi<4;++mi)
#pragma unroll
        for (int ni=0;ni<4;++ni)
            s[mi][ni] = __builtin_amdgcn_mfma_f32_16x16x32_bf16(aq[mi], bk[ni], zero, 0,0,0);

    // ---- scale + (mask|bias), wave-parallel softmax, P -> R pitch 72 ----
    const float* addb = ADD + (size_t)(((wiC*3 + wjC)*8 + w) << 12);
    float rs[4][4];
#pragma unroll
    for (int mi=0;mi<4;++mi){
        const int qbase = mi*16 + g*4;
#pragma unroll
        for (int ni=0;ni<4;++ni){
            const int k = ni*16 + l15;
#pragma unroll
            for (int r=0;r<4;++r)
                s[mi][ni][r] = fmaf(s[mi][ni][r], SCALE_F, addb[((qbase + r) << 6) + k]);
        }
#pragma unroll
        for (int r=0;r<4;++r){
            float m = fmaxf(fmaxf(s[mi][0][r], s[mi][1][r]), fmaxf(s[mi][2][r], s[mi][3][r]));
            m = fmaxf(m, __shfl_xor(m, 1));
            m = fmaxf(m, __shfl_xor(m, 2));
            m = fmaxf(m, __shfl_xor(m, 4));
            m = fmaxf(m, __shfl_xor(m, 8));
            float sum = 0.f;
#pragma unroll
            for (int ni=0;ni<4;++ni){
                float p = __expf(s[mi][ni][r] - m);
                s[mi][ni][r] = p;
                sum += p;
            }
            sum += __shfl_xor(sum, 1);
            sum += __shfl_xor(sum, 2);
            sum += __shfl_xor(sum, 4);
            sum += __shfl_xor(sum, 8);
            rs[mi][r] = 1.f / sum;
            const int q = qbase + r;
#pragma unroll
            for (int ni=0;ni<4;++ni)
                R[q*72 + ni*16 + l15] = f2bs(s[mi][ni][r]);
        }
    }

    // ---- PV: o[64][32] = P @ V  (V via swizzled b128 reads) ----
    f32x4 o[4][2];
#pragma unroll
    for (int mi=0;mi<4;++mi){ o[mi][0]=zero; o[mi][1]=zero; }
    {
        const int sw = (l15 & 7) << 3;
#pragma unroll
        for (int ks=0;ks<2;++ks){
            bf16x8 pa[4], vb[2];
#pragma unroll
            for (int mi=0;mi<4;++mi)
                pa[mi] = *reinterpret_cast<const bf16x8*>(R + (mi*16 + l15)*72 + ks*32 + g*8);
#pragma unroll
            for (int nj=0;nj<2;++nj)
                vb[nj] = *reinterpret_cast<const bf16x8*>(VL + (((nj*16 + l15)*64 + ks*32 + g*8) ^ sw));
#pragma unroll
            for (int mi=0;mi<4;++mi)
#pragma unroll
                for (int nj=0;nj<2;++nj)
                    o[mi][nj] = __builtin_amdgcn_mfma_f32_16x16x32_bf16(pa[mi], vb[nj], o[mi][nj], 0,0,0);
        }
    }

    // ---- att (normalized bf16) -> R pitch 40 (P dead) ----
#pragma unroll
    for (int mi=0;mi<4;++mi)
#pragma unroll
        for (int nj=0;nj<2;++nj)
#pragma unroll
            for (int r=0;r<4;++r)
                R[(mi*16 + g*4 + r)*40 + nj*16 + l15] = f2bs(o[mi][nj][r] * rs[mi][r]);
    __syncthreads();

    // ---- in-block O-GEMM: out[64][256] = att[64][256] @ Wot^T + bo --------
    {
        bf16x8 wf[8][2];
#pragma unroll
        for (int kt=0;kt<8;++kt)
#pragma unroll
            for (int nj=0;nj<2;++nj)
                wf[kt][nj] = *reinterpret_cast<const bf16x8*>(Wot + (size_t)(c0 + nj*16 + l15)*256 + kt*32 + g*8);
        f32x4 acc[4][2];
#pragma unroll
        for (int mi=0;mi<4;++mi){ acc[mi][0]=zero; acc[mi][1]=zero; }
#pragma unroll
        for (int kt=0;kt<8;++kt){
            const short* areg = lds + WB + kt*WSZ;   // wave kt's att (head kt)
            bf16x8 af[4];
#pragma unroll
            for (int mi=0;mi<4;++mi)
                af[mi] = *reinterpret_cast<const bf16x8*>(areg + (mi*16 + l15)*40 + g*8);
#pragma unroll
            for (int mi=0;mi<4;++mi)
#pragma unroll
                for (int nj=0;nj<2;++nj)
                    acc[mi][nj] = __builtin_amdgcn_mfma_f32_16x16x32_bf16(af[mi], wf[kt][nj], acc[mi][nj], 0,0,0);
        }
#pragma unroll
        for (int nj=0;nj<2;++nj){
            const int col = c0 + nj*16 + l15;
            const float bv = bo[col];
#pragma unroll
            for (int mi=0;mi<4;++mi)
#pragma unroll
                for (int r=0;r<4;++r){
                    const int p = mi*16 + g*4 + r;
                    const int pr = ((wi << 3) + (p >> 3) + 4) & 127;
                    const int pc = ((wj << 3) + (p & 7) + 4) & 127;
                    const size_t gp = ((((size_t)b << 7) | pr) << 7) | pc;
                    out[gp * 256 + col] = acc[mi][nj][r] + bv;
                }
        }
    }
}

extern "C" void kernel_launch(void* const* d_in, const int* in_sizes, int n_in,
                              void* d_out, int out_size, void* d_ws, size_t ws_size,
                              hipStream_t stream) {
    const float* x    = (const float*)d_in[0];
    const float* z    = (const float*)d_in[1];
    const float* Wq   = (const float*)d_in[2];
    const float* bq   = (const float*)d_in[3];
    const float* Wkv  = (const float*)d_in[4];
    const float* bkv  = (const float*)d_in[5];
    const float* Wo   = (const float*)d_in[6];
    const float* bo   = (const float*)d_in[7];
    const float* rel  = (const float*)d_in[8];

    char* ws = (char*)d_ws;
    short* Wqt  = (short*)(ws);                    // 128 KiB
    short* Wkvt = (short*)(ws + 131072);           // 256 KiB
    short* Wot  = (short*)(ws + 393216);           // 128 KiB
    float* ADD  = (float*)(ws + 524288);           // 1.125 MiB

    prep_k<<<2176, 256, 0, stream>>>(Wq, Wkv, Wo, rel, Wqt, Wkvt, Wot, ADD);
    fused_k<<<2048, 512, 0, stream>>>(x, z, Wqt, Wkvt, Wot, bq, bkv, bo, ADD, (float*)d_out);
}